// Round 2
// baseline (900.670 us; speedup 1.0000x reference)
//
#include <hip/hip_runtime.h>

typedef __bf16 bf16;
typedef bf16 bf16x4 __attribute__((ext_vector_type(4)));
typedef bf16 bf16x8 __attribute__((ext_vector_type(8)));
typedef float floatx4 __attribute__((ext_vector_type(4)));

#define MFMA(a, b, c) __builtin_amdgcn_mfma_f32_16x16x32_bf16((a), (b), (c), 0, 0, 0)

__device__ __forceinline__ void gl2lds16(const void* g, void* l) {
  __builtin_amdgcn_global_load_lds(
      (const __attribute__((address_space(1))) void*)g,
      (__attribute__((address_space(3))) void*)l, 16, 0, 0);
}

__device__ __forceinline__ bf16x4 cvt4(const float4 v) {
  bf16x4 o;
  o[0] = (bf16)v.x; o[1] = (bf16)v.y; o[2] = (bf16)v.z; o[3] = (bf16)v.w;
  return o;
}

// ---- Kernel 1: W' = bf16(W*gamma); g = W@gamma; cb = W@beta + bias (LN fold) ----
__global__ __launch_bounds__(256) void castw_kernel(
    const float* __restrict__ W, const float* __restrict__ gamma,
    const float* __restrict__ beta, const float* __restrict__ bias,
    bf16* __restrict__ Wb, float* __restrict__ g, float* __restrict__ cb) {
  const int j = blockIdx.x, tid = threadIdx.x;
  const float* wr = W + (size_t)j * 4096;
  float wg = 0.f, wb = 0.f;
  const int base = tid * 16;
#pragma unroll
  for (int i = 0; i < 4; ++i) {
    float4 wv = *(const float4*)(wr + base + i * 4);
    float4 gv = *(const float4*)(gamma + base + i * 4);
    float4 bv = *(const float4*)(beta + base + i * 4);
    float p0 = wv.x * gv.x, p1 = wv.y * gv.y, p2 = wv.z * gv.z, p3 = wv.w * gv.w;
    bf16x4 o; o[0] = (bf16)p0; o[1] = (bf16)p1; o[2] = (bf16)p2; o[3] = (bf16)p3;
    *(bf16x4*)(Wb + (size_t)j * 4096 + base + i * 4) = o;
    wg += p0 + p1 + p2 + p3;
    wb += wv.x * bv.x + wv.y * bv.y + wv.z * bv.z + wv.w * bv.w;
  }
#pragma unroll
  for (int off = 32; off > 0; off >>= 1) {
    wg += __shfl_down(wg, off, 64);
    wb += __shfl_down(wb, off, 64);
  }
  __shared__ float red[8];
  const int w = tid >> 6, lane = tid & 63;
  if (lane == 0) { red[w] = wg; red[4 + w] = wb; }
  __syncthreads();
  if (tid == 0) {
    g[j] = red[0] + red[1] + red[2] + red[3];
    cb[j] = red[4] + red[5] + red[6] + red[7] + bias[j];
  }
}

// ---- Kernel 2: cast x -> bf16 ----
__global__ __launch_bounds__(256) void castx_kernel(const float* __restrict__ x,
                                                    bf16* __restrict__ xb, int n4) {
  int idx = blockIdx.x * 256 + threadIdx.x;
  int stride = gridDim.x * 256;
  const float4* x4 = (const float4*)x;
  for (int i = idx; i < n4; i += stride) *(bf16x4*)(xb + (size_t)i * 4) = cvt4(x4[i]);
}

// ---- Kernel 3: cast p1,p2 -> bf16 (each 1M elements = 262144 float4) ----
__global__ __launch_bounds__(256) void castp_kernel(const float* __restrict__ p1,
                                                    const float* __restrict__ p2,
                                                    bf16* __restrict__ p1b,
                                                    bf16* __restrict__ p2b) {
  int idx = blockIdx.x * 256 + threadIdx.x;
  int stride = gridDim.x * 256;
  const float4* a4 = (const float4*)p1;
  const float4* b4 = (const float4*)p2;
  for (int i = idx; i < 524288; i += stride) {
    if (i < 262144) *(bf16x4*)(p1b + (size_t)i * 4) = cvt4(a4[i]);
    else {
      int k = i - 262144;
      *(bf16x4*)(p2b + (size_t)k * 4) = cvt4(b4[k]);
    }
  }
}

// ---- Kernel 4: block-diagonal MLP, bf16 in, global_load_lds staging, swizzled ----
// grid (64 batch-tiles x 64 r), 256 threads = 4 waves.
// LDS chunk swizzle: 16B chunk s of row holds global chunk g = s ^ (row&7),
// so fragment reads spread across all 8 bank-groups (2 lanes/bank = free).
__global__ __launch_bounds__(256) void blockdiag_kernel(
    const bf16* __restrict__ xb, const bf16* __restrict__ p1b,
    const float* __restrict__ b1, const bf16* __restrict__ p2b,
    const float* __restrict__ b2, bf16* __restrict__ h2) {
  __shared__ bf16 sX[128 * 64];   // swizzled, also reused as sOut
  __shared__ bf16 sP1[64 * 64];   // swizzled
  __shared__ bf16 sP2[64 * 64];   // swizzled
  __shared__ bf16 sH1[128 * 72];  // VALU-written, +8 pad
  __shared__ float sB1[256];
  __shared__ float sB2[64];

  const int tid = threadIdx.x;
  const int bt = blockIdx.x, r = blockIdx.y;
  const size_t b0 = (size_t)bt * 128;

  // stage sX: rows 0..127, 8 chunks each; g constant across i since 32 % 8 == 0
  const int srow = tid >> 3, ss = tid & 7;
  const int sg = ss ^ (srow & 7);
  {
    const bf16* src = xb + (b0 + srow) * 4096 + r * 64 + sg * 8;
#pragma unroll
    for (int i = 0; i < 4; ++i)
      gl2lds16(src + (size_t)i * 32 * 4096, sX + (tid + i * 256) * 8);
  }
  sB1[tid] = b1[r * 256 + tid];
  if (tid < 64) sB2[tid] = b2[r * 64 + tid];

  const int w = tid >> 6, lane = tid & 63;
  const int q = lane >> 4, l16 = lane & 15;
  const int wm = w >> 1, wn = w & 1;

  const bf16* p1base = p1b + (size_t)r * 16384;  // [256][64]
  const bf16* p2base = p2b + (size_t)r * 16384;  // [64][256]

  const floatx4 fzero = {0.f, 0.f, 0.f, 0.f};
  floatx4 acc2[4][2];
#pragma unroll
  for (int mt = 0; mt < 4; ++mt)
#pragma unroll
    for (int nt = 0; nt < 2; ++nt) acc2[mt][nt] = fzero;

  for (int qh = 0; qh < 4; ++qh) {
    if (qh) __syncthreads();  // prev gemm2 reads done before re-staging
#pragma unroll
    for (int i = 0; i < 2; ++i) {
      int row = srow + i * 32;  // 0..63
      gl2lds16(p1base + (size_t)(qh * 64 + row) * 64 + sg * 8, sP1 + (tid + i * 256) * 8);
      gl2lds16(p2base + (size_t)row * 256 + qh * 64 + sg * 8, sP2 + (tid + i * 256) * 8);
    }
    __syncthreads();  // staging complete (also covers sX first iter)

    // GEMM1: H1q[b, m] = relu(sum_k X[b,k] P1[m,k] + b1)
    floatx4 acc1[4][2];
#pragma unroll
    for (int mt = 0; mt < 4; ++mt)
#pragma unroll
      for (int nt = 0; nt < 2; ++nt) acc1[mt][nt] = fzero;
#pragma unroll
    for (int ks = 0; ks < 2; ++ks) {
      const int co = ((ks * 4 + q) ^ (l16 & 7)) * 8;
      bf16x8 a[4], bb[2];
#pragma unroll
      for (int mt = 0; mt < 4; ++mt)
        a[mt] = *(const bf16x8*)(&sX[(64 * wm + mt * 16 + l16) * 64 + co]);
#pragma unroll
      for (int nt = 0; nt < 2; ++nt)
        bb[nt] = *(const bf16x8*)(&sP1[(32 * wn + nt * 16 + l16) * 64 + co]);
#pragma unroll
      for (int mt = 0; mt < 4; ++mt)
#pragma unroll
        for (int nt = 0; nt < 2; ++nt) acc1[mt][nt] = MFMA(a[mt], bb[nt], acc1[mt][nt]);
    }
#pragma unroll
    for (int mt = 0; mt < 4; ++mt) {
#pragma unroll
      for (int nt = 0; nt < 2; ++nt) {
        int c = 32 * wn + nt * 16 + l16;
        float bias1v = sB1[qh * 64 + c];
#pragma unroll
        for (int v = 0; v < 4; ++v) {
          int row = 64 * wm + mt * 16 + q * 4 + v;
          sH1[row * 72 + c] = (bf16)fmaxf(acc1[mt][nt][v] + bias1v, 0.f);
        }
      }
    }
    __syncthreads();  // sH1 ready

    // GEMM2 partial: C2[b, kk] += sum_m H1q[b,m] P2[kk,m]
#pragma unroll
    for (int ks = 0; ks < 2; ++ks) {
      const int co = ((ks * 4 + q) ^ (l16 & 7)) * 8;
      bf16x8 a2[4], bb2[2];
#pragma unroll
      for (int mt = 0; mt < 4; ++mt)
        a2[mt] = *(const bf16x8*)(&sH1[(64 * wm + mt * 16 + l16) * 72 + ks * 32 + q * 8]);
#pragma unroll
      for (int nt = 0; nt < 2; ++nt)
        bb2[nt] = *(const bf16x8*)(&sP2[(32 * wn + nt * 16 + l16) * 64 + co]);
#pragma unroll
      for (int mt = 0; mt < 4; ++mt)
#pragma unroll
        for (int nt = 0; nt < 2; ++nt) acc2[mt][nt] = MFMA(a2[mt], bb2[nt], acc2[mt][nt]);
    }
  }

  // epilogue: bias2+relu -> swizzled sOut (reuse sX; safe: all gemm1 reads of sX
  // completed before the last mid-quarter barrier) -> coalesced 16B stores
#pragma unroll
  for (int mt = 0; mt < 4; ++mt) {
#pragma unroll
    for (int nt = 0; nt < 2; ++nt) {
      int col = 32 * wn + nt * 16 + l16;
      float b2v = sB2[col];
#pragma unroll
      for (int v = 0; v < 4; ++v) {
        int row = 64 * wm + mt * 16 + q * 4 + v;
        float val = fmaxf(acc2[mt][nt][v] + b2v, 0.f);
        sX[row * 64 + ((col >> 3) ^ (row & 7)) * 8 + (col & 7)] = (bf16)val;
      }
    }
  }
  __syncthreads();
  {
    bf16* dst = h2 + (b0 + srow) * 4096 + r * 64 + sg * 8;
#pragma unroll
    for (int i = 0; i < 4; ++i) {
      bf16x8 vv = *(const bf16x8*)(sX + (tid + i * 256) * 8);
      *(bf16x8*)(dst + (size_t)i * 32 * 4096) = vv;
    }
  }
}

// ---- Kernel 5: per-row LN stats (mu, rsig) from bf16 h ----
__global__ __launch_bounds__(256) void stats_kernel(const bf16* __restrict__ h,
                                                    float* __restrict__ mu,
                                                    float* __restrict__ rs) {
  const int row = blockIdx.x, tid = threadIdx.x;
  const bf16* hr = h + (size_t)row * 4096;
  float s = 0.f, ss = 0.f;
#pragma unroll
  for (int i = 0; i < 2; ++i) {
    bf16x8 v = *(const bf16x8*)(hr + (size_t)(i * 256 + tid) * 8);
#pragma unroll
    for (int j = 0; j < 8; ++j) {
      float f = (float)v[j];
      s += f; ss += f * f;
    }
  }
#pragma unroll
  for (int off = 32; off > 0; off >>= 1) {
    s += __shfl_down(s, off, 64);
    ss += __shfl_down(ss, off, 64);
  }
  __shared__ float red[8];
  const int w = tid >> 6, lane = tid & 63;
  if (lane == 0) { red[w] = s; red[4 + w] = ss; }
  __syncthreads();
  if (tid == 0) {
    float st = red[0] + red[1] + red[2] + red[3];
    float sst = red[4] + red[5] + red[6] + red[7];
    float m = st * (1.f / 4096.f);
    mu[row] = m;
    rs[row] = rsqrtf(sst * (1.f / 4096.f) - m * m + 1e-5f);
  }
}

// ---- Kernel 6: out = relu(rs_b*(h@W'^T - mu_b*g) + cb) + x ----
// 128x128 tile, BK=64 (half the barrier drains of BK=32), swizzled LDS chunks.
__global__ __launch_bounds__(256) void gemm_kernel(
    const bf16* __restrict__ A, const bf16* __restrict__ B,
    const float* __restrict__ g, const float* __restrict__ cb,
    const float* __restrict__ mu, const float* __restrict__ rs,
    const float* __restrict__ xres, float* __restrict__ out) {
  __shared__ bf16 sA[128 * 64];
  __shared__ bf16 sB[128 * 64];
  const int tid = threadIdx.x;
  const int n0 = blockIdx.x * 128;
  const int m0 = blockIdx.y * 128;
  const int w = tid >> 6, lane = tid & 63;
  const int q = lane >> 4, l16 = lane & 15;
  const int wm = w >> 1, wn = w & 1;

  const floatx4 fzero = {0.f, 0.f, 0.f, 0.f};
  floatx4 acc[4][4];
#pragma unroll
  for (int mt = 0; mt < 4; ++mt)
#pragma unroll
    for (int nt = 0; nt < 4; ++nt) acc[mt][nt] = fzero;

  const int srow = tid >> 3, ss = tid & 7;
  const int sg = ss ^ (srow & 7);
  const bf16* aptr = A + (size_t)(m0 + srow) * 4096 + sg * 8;
  const bf16* bptr = B + (size_t)(n0 + srow) * 4096 + sg * 8;

  const int co0 = (q ^ (l16 & 7)) * 8;        // ks=0 chunk = q
  const int co1 = ((4 + q) ^ (l16 & 7)) * 8;  // ks=1 chunk = 4+q

  for (int k0 = 0; k0 < 4096; k0 += 64) {
#pragma unroll
    for (int i = 0; i < 4; ++i) {
      gl2lds16(aptr + (size_t)i * 32 * 4096, sA + (tid + i * 256) * 8);
      gl2lds16(bptr + (size_t)i * 32 * 4096, sB + (tid + i * 256) * 8);
    }
    aptr += 64;
    bptr += 64;
    __syncthreads();
    bf16x8 af[4], bfr[4];
    // ks = 0
#pragma unroll
    for (int mt = 0; mt < 4; ++mt)
      af[mt] = *(const bf16x8*)(&sA[(64 * wm + mt * 16 + l16) * 64 + co0]);
#pragma unroll
    for (int nt = 0; nt < 4; ++nt)
      bfr[nt] = *(const bf16x8*)(&sB[(64 * wn + nt * 16 + l16) * 64 + co0]);
#pragma unroll
    for (int mt = 0; mt < 4; ++mt)
#pragma unroll
      for (int nt = 0; nt < 4; ++nt) acc[mt][nt] = MFMA(af[mt], bfr[nt], acc[mt][nt]);
    // ks = 1
#pragma unroll
    for (int mt = 0; mt < 4; ++mt)
      af[mt] = *(const bf16x8*)(&sA[(64 * wm + mt * 16 + l16) * 64 + co1]);
#pragma unroll
    for (int nt = 0; nt < 4; ++nt)
      bfr[nt] = *(const bf16x8*)(&sB[(64 * wn + nt * 16 + l16) * 64 + co1]);
#pragma unroll
    for (int mt = 0; mt < 4; ++mt)
#pragma unroll
      for (int nt = 0; nt < 4; ++nt) acc[mt][nt] = MFMA(af[mt], bfr[nt], acc[mt][nt]);
    __syncthreads();
  }

  // epilogue with folded LayerNorm
  float muv[16], rsv[16];
#pragma unroll
  for (int mt = 0; mt < 4; ++mt)
#pragma unroll
    for (int v = 0; v < 4; ++v) {
      int row = m0 + 64 * wm + mt * 16 + q * 4 + v;
      muv[mt * 4 + v] = mu[row];
      rsv[mt * 4 + v] = rs[row];
    }
#pragma unroll
  for (int nt = 0; nt < 4; ++nt) {
    const int col = n0 + 64 * wn + nt * 16 + l16;
    const float gj = g[col];
    const float cbj = cb[col];
#pragma unroll
    for (int mt = 0; mt < 4; ++mt) {
#pragma unroll
      for (int v = 0; v < 4; ++v) {
        const int row = m0 + 64 * wm + mt * 16 + q * 4 + v;
        const size_t o = (size_t)row * 4096 + col;
        float val = rsv[mt * 4 + v] * (acc[mt][nt][v] - muv[mt * 4 + v] * gj) + cbj;
        out[o] = fmaxf(val, 0.f) + xres[o];
      }
    }
  }
}

extern "C" void kernel_launch(void* const* d_in, const int* in_sizes, int n_in,
                              void* d_out, int out_size, void* d_ws, size_t ws_size,
                              hipStream_t stream) {
  const float* x = (const float*)d_in[0];
  const float* p1 = (const float*)d_in[1];
  const float* b1 = (const float*)d_in[2];
  const float* p2 = (const float*)d_in[3];
  const float* b2 = (const float*)d_in[4];
  const float* gamma = (const float*)d_in[5];
  const float* beta = (const float*)d_in[6];
  const float* W = (const float*)d_in[7];
  const float* bias = (const float*)d_in[8];
  float* out = (float*)d_out;

  const size_t MB = 1ull << 20;
  // ws: [0,32M) W' bf16; [32M,96M) h bf16; then LN-fold scalars (~96K)
  bf16* Wb = (bf16*)d_ws;
  bf16* h = (bf16*)((char*)d_ws + 32 * MB);
  float* mu = (float*)((char*)d_ws + 96 * MB);
  float* rs = mu + 8192;
  float* gv = rs + 8192;
  float* cb = gv + 4096;
  // d_out doubles as scratch until gemm overwrites it:
  // [0,64M) xb bf16; [64M,66M) p1b; [66M,68M) p2b — all consumed by blockdiag.
  bf16* xb = (bf16*)d_out;
  bf16* p1b = (bf16*)((char*)d_out + 64 * MB);
  bf16* p2b = (bf16*)((char*)d_out + 66 * MB);

  castw_kernel<<<4096, 256, 0, stream>>>(W, gamma, beta, bias, Wb, gv, cb);
  castx_kernel<<<4096, 256, 0, stream>>>(x, xb, 8192 * 4096 / 4);
  castp_kernel<<<512, 256, 0, stream>>>(p1, p2, p1b, p2b);
  blockdiag_kernel<<<dim3(64, 64), 256, 0, stream>>>(xb, p1b, b1, p2b, b2, h);
  stats_kernel<<<8192, 256, 0, stream>>>(h, mu, rs);
  gemm_kernel<<<dim3(32, 64), 256, 0, stream>>>(h, Wb, gv, cb, mu, rs, x, out);
}